// Round 3
// baseline (306.261 us; speedup 1.0000x reference)
//
#include <hip/hip_runtime.h>
#include <hip/hip_bf16.h>

#define NN 16384
#define EE 524288
#define DDIM 128
#define HDIM 256
#define CDIM 10
#define GG 64
#define MAXD 128
#define WPR 512   // bitmap words per row = NN/32

// workspace byte offsets (aliased; kernels are sequential on one stream)
#define OFF_BM   0ull          // 32 MB bitmap, dead after extract
#define OFF_Y1   0ull          // 8 MB   (alias BM)
#define OFF_H1   8388608ull    // 16 MB  (alias BM)
#define OFF_Y2   25165824ull   // 16 MB  (tail aliases BM, rest fresh)
#define OFF_ELL  41943040ull   // 8 MB
#define OFF_DIS  50331648ull   // 64 KB
#define OFF_DEG  50397184ull   // 64 KB
#define OFF_H2   0ull          // 16 MB  (alias Y1/H1, both dead by then)
#define OFF_POOL 50462720ull   // 64 KB
#define OFF_CNT  50528256ull   // 256 B

// zero the bitmap AND plant the self-loop bits in one pass
__global__ void zero_selfloop(uint4* p) {
    int i = blockIdx.x * blockDim.x + threadIdx.x;
    int stride = gridDim.x * blockDim.x;
    const int n16 = NN * WPR / 4;  // 2M uint4
    for (; i < n16; i += stride) {
        uint4 z = make_uint4(0u, 0u, 0u, 0u);
        int r = i >> 7;       // row (128 uint4 slots per row)
        int slot = i & 127;   // which uint4 within the row
        int sw = r >> 5;      // self word index within row
        if ((sw >> 2) == slot) {
            unsigned bit = 1u << (r & 31);
            int comp = sw & 3;
            if (comp == 0) z.x = bit;
            else if (comp == 1) z.y = bit;
            else if (comp == 2) z.z = bit;
            else z.w = bit;
        }
        p[i] = z;
    }
}

__global__ void zero_f(float* p, int n) {
    int i = blockIdx.x * blockDim.x + threadIdx.x;
    if (i < n) p[i] = 0.0f;
}

__global__ void edge_kernel(const int* __restrict__ ei, unsigned* bm) {
    int e = blockIdx.x * blockDim.x + threadIdx.x;
    if (e < EE) {
        int s = ei[e];
        int d = ei[EE + e];
        atomicOr(&bm[s * WPR + (d >> 5)], 1u << (d & 31));
    }
}

// one wave per row: popcount + prefix scan -> ELL cols (sorted), deg, dis
__global__ void extract_kernel(const unsigned* __restrict__ bm,
                               int* __restrict__ ell, int* __restrict__ deg,
                               float* __restrict__ dis) {
    int gtid = blockIdx.x * blockDim.x + threadIdx.x;
    int row  = gtid >> 6;
    int lane = threadIdx.x & 63;
    if (row >= NN) return;
    const uint4* wp = (const uint4*)(bm + (size_t)row * WPR + lane * 8);
    uint4 a = wp[0];
    uint4 b = wp[1];
    unsigned w[8] = {a.x, a.y, a.z, a.w, b.x, b.y, b.z, b.w};
    int pc = 0;
#pragma unroll
    for (int k = 0; k < 8; k++) pc += __popc(w[k]);
    // inclusive scan
    int pre = pc;
#pragma unroll
    for (int off = 1; off < 64; off <<= 1) {
        int o = __shfl_up(pre, off, 64);
        if (lane >= off) pre += o;
    }
    int total = __shfl(pre, 63, 64);
    pre -= pc;  // exclusive
    int base = row * MAXD;
    int pos = pre;
#pragma unroll
    for (int k = 0; k < 8; k++) {
        unsigned bits = w[k];
        int cbase = lane * 256 + k * 32;
        while (bits) {
            int bit = __ffs(bits) - 1;
            if (pos < MAXD) ell[base + pos] = cbase + bit;
            pos++;
            bits &= bits - 1;
        }
    }
    if (lane == 0) {
        deg[row] = total < MAXD ? total : MAXD;
        dis[row] = 1.0f / sqrtf((float)total);
    }
}

// y[row,:] = dis[row] * sum_k dis[c_k] * x[c_k,:]
// One block (256 thr, 4 waves) per row. Each wave reads a FULL source row per
// VMEM instr (VEC floats per lane), waves split the neighbor list, LDS reduce.
template <int DC>
__global__ __launch_bounds__(256) void spmm_vec(const float* __restrict__ x,
                                                const int* __restrict__ ell,
                                                const int* __restrict__ deg,
                                                const float* __restrict__ dis,
                                                float* __restrict__ y) {
    constexpr int VEC = DC / 64;   // floats per lane (2 for 128, 4 for 256)
    __shared__ int2  scw[MAXD];    // (col, bitcast dis[col])
    __shared__ float red[4][DC];
    const int row  = blockIdx.x;
    const int t    = threadIdx.x;
    const int wv   = t >> 6;
    const int lane = t & 63;
    const int d    = deg[row];
    if (t < d) {
        int c = ell[row * MAXD + t];
        scw[t] = make_int2(c, __float_as_int(dis[c]));
    }
    __syncthreads();

    float acc[VEC];
#pragma unroll
    for (int j = 0; j < VEC; j++) acc[j] = 0.0f;

#pragma unroll 2
    for (int k = wv; k < d; k += 4) {
        int2 p = scw[k];
        float wgt = __int_as_float(p.y);
        const float* src = x + (size_t)p.x * DC + lane * VEC;
#pragma unroll
        for (int j = 0; j < VEC; j += 4) {
            if (VEC >= 4) {
                float4 v = *(const float4*)(src + j);
                acc[j + 0] = fmaf(wgt, v.x, acc[j + 0]);
                acc[j + 1] = fmaf(wgt, v.y, acc[j + 1]);
                acc[j + 2] = fmaf(wgt, v.z, acc[j + 2]);
                acc[j + 3] = fmaf(wgt, v.w, acc[j + 3]);
            }
        }
        if (VEC == 2) {
            float2 v = *(const float2*)src;
            acc[0] = fmaf(wgt, v.x, acc[0]);
            acc[1] = fmaf(wgt, v.y, acc[1]);
        }
    }

    // wave partials -> LDS
    if (VEC == 4) {
        *(float4*)&red[wv][lane * 4] = make_float4(acc[0], acc[1], acc[2], acc[3]);
    } else {
        *(float2*)&red[wv][lane * 2] = make_float2(acc[0], acc[1]);
    }
    __syncthreads();
    if (t < DC) {
        float s = red[0][t] + red[1][t] + red[2][t] + red[3][t];
        y[(size_t)row * DC + t] = dis[row] * s;
    }
}

// H = relu(Y @ W + b); Y:[M,K] row-major, W:[K,256] row-major, H:[M,256].
// Block tile: 128 rows x 64 cols, 128 threads, 8x8 micro-tile.
template <int K>
__global__ __launch_bounds__(128) void gemm_relu_tile(
        const float* __restrict__ Y, const float* __restrict__ W,
        const float* __restrict__ bias, float* __restrict__ H) {
    __shared__ float As[32][132];  // [k][row]
    __shared__ float Bs[32][68];   // [k][col]
    const int r0 = blockIdx.x * 128;
    const int c0 = blockIdx.y * 64;
    const int t = threadIdx.x;
    const int tx = t & 7;
    const int ty = t >> 3;

    float acc[8][8];
#pragma unroll
    for (int i = 0; i < 8; i++)
#pragma unroll
        for (int j = 0; j < 8; j++) acc[i][j] = 0.0f;

    for (int d0 = 0; d0 < K; d0 += 32) {
        {
            const float* src = Y + (size_t)(r0 + t) * K + d0;
            float4 av[8];
#pragma unroll
            for (int q = 0; q < 8; q++) av[q] = ((const float4*)src)[q];
#pragma unroll
            for (int q = 0; q < 8; q++) {
                As[q * 4 + 0][t] = av[q].x;
                As[q * 4 + 1][t] = av[q].y;
                As[q * 4 + 2][t] = av[q].z;
                As[q * 4 + 3][t] = av[q].w;
            }
        }
        {
            int bk = t >> 2;
            int bc = (t & 3) * 16;
            const float* wsrc = W + (size_t)(d0 + bk) * 256 + c0 + bc;
#pragma unroll
            for (int q = 0; q < 4; q++) {
                float4 wvv = ((const float4*)wsrc)[q];
                *(float4*)&Bs[bk][bc + q * 4] = wvv;
            }
        }
        __syncthreads();
#pragma unroll
        for (int k = 0; k < 32; k++) {
            float a[8], b[8];
            *(float4*)&a[0] = *(const float4*)&As[k][ty * 8];
            *(float4*)&a[4] = *(const float4*)&As[k][ty * 8 + 4];
            *(float4*)&b[0] = *(const float4*)&Bs[k][tx * 8];
            *(float4*)&b[4] = *(const float4*)&Bs[k][tx * 8 + 4];
#pragma unroll
            for (int i = 0; i < 8; i++)
#pragma unroll
                for (int j = 0; j < 8; j++)
                    acc[i][j] = fmaf(a[i], b[j], acc[i][j]);
        }
        __syncthreads();
    }

    float bv[8];
#pragma unroll
    for (int j = 0; j < 8; j++) bv[j] = bias[c0 + tx * 8 + j];
#pragma unroll
    for (int i = 0; i < 8; i++) {
        float4 o0, o1;
        o0.x = fmaxf(acc[i][0] + bv[0], 0.0f);
        o0.y = fmaxf(acc[i][1] + bv[1], 0.0f);
        o0.z = fmaxf(acc[i][2] + bv[2], 0.0f);
        o0.w = fmaxf(acc[i][3] + bv[3], 0.0f);
        o1.x = fmaxf(acc[i][4] + bv[4], 0.0f);
        o1.y = fmaxf(acc[i][5] + bv[5], 0.0f);
        o1.z = fmaxf(acc[i][6] + bv[6], 0.0f);
        o1.w = fmaxf(acc[i][7] + bv[7], 0.0f);
        float* dst = H + (size_t)(r0 + ty * 8 + i) * 256 + c0 + tx * 8;
        ((float4*)dst)[0] = o0;
        ((float4*)dst)[1] = o1;
    }
}

// counts per graph
__global__ void count_kernel(const int* __restrict__ batch, float* cnt) {
    __shared__ int h[GG];
    int t = threadIdx.x;
    if (t < GG) h[t] = 0;
    __syncthreads();
    int i = blockIdx.x * blockDim.x + t;
    if (i < NN) atomicAdd(&h[batch[i]], 1);
    __syncthreads();
    if (t < GG && h[t] > 0) atomicAdd(&cnt[t], (float)h[t]);
}

// segment-sum 64 nodes per block (batch sorted -> run-length accumulate)
__global__ void pool_kernel(const float* __restrict__ h2,
                            const int* __restrict__ batch,
                            float* __restrict__ pooled) {
    int b = blockIdx.x;
    int t = threadIdx.x;  // feature dim, 256
    int n0 = b * 64;
    int cur = batch[n0];
    float acc = 0.0f;
    for (int n = 0; n < 64; n++) {
        int node = n0 + n;
        int g = batch[node];
        if (g != cur) {
            atomicAdd(&pooled[cur * 256 + t], acc);
            acc = 0.0f;
            cur = g;
        }
        acc += h2[node * 256 + t];
    }
    atomicAdd(&pooled[cur * 256 + t], acc);
}

// out[g,c] = (pooled[g,:]/cnt[g]) . Wc[:,c] + bc[c]
__global__ void head_kernel(const float* __restrict__ pooled,
                            const float* __restrict__ cnt,
                            const float* __restrict__ Wc,
                            const float* __restrict__ bc,
                            float* __restrict__ out) {
    int g = blockIdx.x;
    int l = threadIdx.x;  // 64
    float inv = 1.0f / fmaxf(cnt[g], 1.0f);
    float acc[CDIM];
#pragma unroll
    for (int c = 0; c < CDIM; c++) acc[c] = 0.0f;
    for (int t = l; t < 256; t += 64) {
        float pv = pooled[g * 256 + t] * inv;
#pragma unroll
        for (int c = 0; c < CDIM; c++) acc[c] = fmaf(pv, Wc[t * CDIM + c], acc[c]);
    }
#pragma unroll
    for (int c = 0; c < CDIM; c++) {
        float v = acc[c];
        for (int off = 32; off > 0; off >>= 1) v += __shfl_down(v, off, 64);
        if (l == 0) out[g * CDIM + c] = v + bc[c];
    }
}

extern "C" void kernel_launch(void* const* d_in, const int* in_sizes, int n_in,
                              void* d_out, int out_size, void* d_ws, size_t ws_size,
                              hipStream_t stream) {
    const float* x  = (const float*)d_in[0];
    const int*   ei = (const int*)d_in[1];
    const int*   batch = (const int*)d_in[2];
    const float* W1 = (const float*)d_in[3];
    const float* b1 = (const float*)d_in[4];
    const float* W2 = (const float*)d_in[5];
    const float* b2 = (const float*)d_in[6];
    const float* Wc = (const float*)d_in[7];
    const float* bc = (const float*)d_in[8];
    float* out = (float*)d_out;

    char* ws = (char*)d_ws;
    unsigned* bm  = (unsigned*)(ws + OFF_BM);
    float* y1     = (float*)(ws + OFF_Y1);
    float* h1     = (float*)(ws + OFF_H1);
    float* y2     = (float*)(ws + OFF_Y2);
    int*   ell    = (int*)(ws + OFF_ELL);
    float* dis    = (float*)(ws + OFF_DIS);
    int*   deg    = (int*)(ws + OFF_DEG);
    float* h2     = (float*)(ws + OFF_H2);
    float* pooled = (float*)(ws + OFF_POOL);
    float* cnt    = (float*)(ws + OFF_CNT);

    // 1) zero 32MB bitmap + self-loop bits (fused)
    zero_selfloop<<<2048, 256, 0, stream>>>((uint4*)bm);
    // 2) edges
    edge_kernel<<<EE / 256, 256, 0, stream>>>(ei, bm);
    // 3) bitmap -> ELL + deg + dis (wave per row)
    extract_kernel<<<(NN * 64) / 256, 256, 0, stream>>>(bm, ell, deg, dis);
    // 4) SpMM1: y1 = Ahat @ x   [N,128]
    spmm_vec<DDIM><<<NN, 256, 0, stream>>>(x, ell, deg, dis, y1);
    // 5) GEMM1: h1 = relu(y1 @ W1 + b1)  [N,256]
    {
        dim3 grid(NN / 128, 256 / 64);
        gemm_relu_tile<DDIM><<<grid, 128, 0, stream>>>(y1, W1, b1, h1);
    }
    // 6) SpMM2: y2 = Ahat @ h1  [N,256]
    spmm_vec<HDIM><<<NN, 256, 0, stream>>>(h1, ell, deg, dis, y2);
    // 7) GEMM2: h2 = relu(y2 @ W2 + b2) [N,256]
    {
        dim3 grid(NN / 128, 256 / 64);
        gemm_relu_tile<HDIM><<<grid, 128, 0, stream>>>(y2, W2, b2, h2);
    }
    // 8) pooled mean
    zero_f<<<(GG * 256 + GG + 255) / 256, 256, 0, stream>>>(pooled, GG * 256 + GG);
    count_kernel<<<NN / 256, 256, 0, stream>>>(batch, cnt);
    pool_kernel<<<NN / 64, 256, 0, stream>>>(h2, batch, pooled);
    // 9) head
    head_kernel<<<GG, 64, 0, stream>>>(pooled, cnt, Wc, bc, out);
}

// Round 5
// 292.987 us; speedup vs baseline: 1.0453x; 1.0453x over previous
//
#include <hip/hip_runtime.h>
#include <hip/hip_bf16.h>
#include <hip/hip_fp16.h>

#define NN 16384
#define EE 524288
#define DDIM 128
#define HDIM 256
#define CDIM 10
#define GG 64
#define MAXD 128
#define WPR 512   // bitmap words per row = NN/32

typedef unsigned short us8 __attribute__((ext_vector_type(8)));

// workspace byte offsets (aliased; kernels are sequential on one stream)
#define OFF_BM   0ull          // 32 MB bitmap [0, 33554432), dead after extract
#define OFF_Y1   0ull          // 8 MB fp32 (alias BM, written post-extract)
#define OFF_H1   8388608ull    // 8 MB fp16, 2 planes of [NN][128] (alias BM)
#define OFF_Y2   16777216ull   // 16 MB fp32 (alias BM tail)
#define OFF_XH   33554432ull   // 4 MB fp16 x (disjoint from BM)
#define OFF_ELL  37748736ull   // 4 MB ushort ELL
#define OFF_DIS  41943040ull   // 64 KB
#define OFF_DEG  42008576ull   // 64 KB
#define OFF_POOL 42074112ull   // 64 KB (16384 floats)
#define OFF_CNT  42139648ull   // 256 B (64 floats, contiguous after POOL)

__global__ void cvt_f16(const float* __restrict__ in, __half* __restrict__ out) {
    int i = (blockIdx.x * blockDim.x + threadIdx.x) * 4;
    float4 v = *(const float4*)(in + i);
    __half2 a = __floats2half2_rn(v.x, v.y);
    __half2 b = __floats2half2_rn(v.z, v.w);
    *(__half2*)(out + i)     = a;
    *(__half2*)(out + i + 2) = b;
}

// zero the bitmap AND plant the self-loop bits in one pass
__global__ void zero_selfloop(uint4* p) {
    int i = blockIdx.x * blockDim.x + threadIdx.x;
    int stride = gridDim.x * blockDim.x;
    const int n16 = NN * WPR / 4;  // 2M uint4
    for (; i < n16; i += stride) {
        uint4 z = make_uint4(0u, 0u, 0u, 0u);
        int r = i >> 7;       // row (128 uint4 slots per row)
        int slot = i & 127;   // which uint4 within the row
        int sw = r >> 5;      // self word index within row
        if ((sw >> 2) == slot) {
            unsigned bit = 1u << (r & 31);
            int comp = sw & 3;
            if (comp == 0) z.x = bit;
            else if (comp == 1) z.y = bit;
            else if (comp == 2) z.z = bit;
            else z.w = bit;
        }
        p[i] = z;
    }
}

__global__ void zero_f(float* p, int n) {
    int i = blockIdx.x * blockDim.x + threadIdx.x;
    if (i < n) p[i] = 0.0f;
}

__global__ void edge_kernel(const int* __restrict__ ei, unsigned* bm) {
    int e = blockIdx.x * blockDim.x + threadIdx.x;
    if (e < EE) {
        int s = ei[e];
        int d = ei[EE + e];
        atomicOr(&bm[s * WPR + (d >> 5)], 1u << (d & 31));
    }
}

// one wave per row: popcount + prefix scan -> ELL cols (ushort), deg, dis
__global__ void extract_kernel(const unsigned* __restrict__ bm,
                               unsigned short* __restrict__ ell, int* __restrict__ deg,
                               float* __restrict__ dis) {
    int gtid = blockIdx.x * blockDim.x + threadIdx.x;
    int row  = gtid >> 6;
    int lane = threadIdx.x & 63;
    if (row >= NN) return;
    const uint4* wp = (const uint4*)(bm + (size_t)row * WPR + lane * 8);
    uint4 a = wp[0];
    uint4 b = wp[1];
    unsigned w[8] = {a.x, a.y, a.z, a.w, b.x, b.y, b.z, b.w};
    int pc = 0;
#pragma unroll
    for (int k = 0; k < 8; k++) pc += __popc(w[k]);
    int pre = pc;
#pragma unroll
    for (int off = 1; off < 64; off <<= 1) {
        int o = __shfl_up(pre, off, 64);
        if (lane >= off) pre += o;
    }
    int total = __shfl(pre, 63, 64);
    pre -= pc;  // exclusive
    int base = row * MAXD;
    int pos = pre;
#pragma unroll
    for (int k = 0; k < 8; k++) {
        unsigned bits = w[k];
        int cbase = lane * 256 + k * 32;
        while (bits) {
            int bit = __ffs(bits) - 1;
            if (pos < MAXD) ell[base + pos] = (unsigned short)(cbase + bit);
            pos++;
            bits &= bits - 1;
        }
    }
    if (lane == 0) {
        deg[row] = total < MAXD ? total : MAXD;
        dis[row] = 1.0f / sqrtf((float)total);
    }
}

// y[row, p*128+t] = dis[row] * sum_k dis[c_k] * src[p][c_k][t]
// src: [P][NN][128] fp16 planes (each 4 MB -> per-XCD L2 resident per pass).
// grid (NN, P), blockIdx.y slowest => temporal pass phases.
__global__ __launch_bounds__(256) void spmm_f16(const __half* __restrict__ src,
                                                const unsigned short* __restrict__ ell,
                                                const int* __restrict__ deg,
                                                const float* __restrict__ dis,
                                                float* __restrict__ y, int P) {
    __shared__ int2  scw[MAXD];
    __shared__ float red[4][128];
    const int row  = blockIdx.x;
    const int p    = blockIdx.y;
    const int t    = threadIdx.x;
    const int wv   = t >> 6;
    const int lane = t & 63;
    const int d    = deg[row];
    if (t < d) {
        int c = ell[row * MAXD + t];
        scw[t] = make_int2(c, __float_as_int(dis[c]));
    }
    __syncthreads();

    const __half* plane = src + (size_t)p * NN * 128;
    float a0 = 0.0f, a1 = 0.0f;
#pragma unroll 2
    for (int k = wv; k < d; k += 4) {
        int2 pr = scw[k];
        float wgt = __int_as_float(pr.y);
        __half2 h = *(const __half2*)(plane + (size_t)pr.x * 128 + lane * 2);
        float2 f = __half22float2(h);
        a0 = fmaf(wgt, f.x, a0);
        a1 = fmaf(wgt, f.y, a1);
    }
    *(float2*)&red[wv][lane * 2] = make_float2(a0, a1);
    __syncthreads();
    if (t < 128) {
        float s = red[0][t] + red[1][t] + red[2][t] + red[3][t];
        y[(size_t)row * (P * 128) + p * 128 + t] = dis[row] * s;
    }
}

// GEMM1: H = relu(Y @ W + b) written as fp16 into 2 column planes.
// Y:[M,K] fp32, W:[K,256], H: [2][M][128] fp16.
template <int K>
__global__ __launch_bounds__(128) void gemm_relu_f16(
        const float* __restrict__ Y, const float* __restrict__ W,
        const float* __restrict__ bias, __half* __restrict__ H) {
    __shared__ float As[32][132];
    __shared__ float Bs[32][68];
    const int r0 = blockIdx.x * 128;
    const int c0 = blockIdx.y * 64;
    const int t = threadIdx.x;
    const int tx = t & 7;
    const int ty = t >> 3;

    float acc[8][8];
#pragma unroll
    for (int i = 0; i < 8; i++)
#pragma unroll
        for (int j = 0; j < 8; j++) acc[i][j] = 0.0f;

    for (int d0 = 0; d0 < K; d0 += 32) {
        {
            const float* src = Y + (size_t)(r0 + t) * K + d0;
            float4 av[8];
#pragma unroll
            for (int q = 0; q < 8; q++) av[q] = ((const float4*)src)[q];
#pragma unroll
            for (int q = 0; q < 8; q++) {
                As[q * 4 + 0][t] = av[q].x;
                As[q * 4 + 1][t] = av[q].y;
                As[q * 4 + 2][t] = av[q].z;
                As[q * 4 + 3][t] = av[q].w;
            }
        }
        {
            int bk = t >> 2;
            int bc = (t & 3) * 16;
            const float* wsrc = W + (size_t)(d0 + bk) * 256 + c0 + bc;
#pragma unroll
            for (int q = 0; q < 4; q++) {
                float4 wvv = ((const float4*)wsrc)[q];
                *(float4*)&Bs[bk][bc + q * 4] = wvv;
            }
        }
        __syncthreads();
#pragma unroll
        for (int k = 0; k < 32; k++) {
            float a[8], b[8];
            *(float4*)&a[0] = *(const float4*)&As[k][ty * 8];
            *(float4*)&a[4] = *(const float4*)&As[k][ty * 8 + 4];
            *(float4*)&b[0] = *(const float4*)&Bs[k][tx * 8];
            *(float4*)&b[4] = *(const float4*)&Bs[k][tx * 8 + 4];
#pragma unroll
            for (int i = 0; i < 8; i++)
#pragma unroll
                for (int j = 0; j < 8; j++)
                    acc[i][j] = fmaf(a[i], b[j], acc[i][j]);
        }
        __syncthreads();
    }

    float bv[8];
#pragma unroll
    for (int j = 0; j < 8; j++) bv[j] = bias[c0 + tx * 8 + j];
    const int cbase = c0 + tx * 8;
    const int pl = cbase >> 7;          // column plane
    const int cw = cbase & 127;         // col within plane
#pragma unroll
    for (int i = 0; i < 8; i++) {
        __half hv[8];
#pragma unroll
        for (int j = 0; j < 8; j++) hv[j] = __float2half(fmaxf(acc[i][j] + bv[j], 0.0f));
        *(us8*)(H + (size_t)pl * NN * 128 + (size_t)(r0 + ty * 8 + i) * 128 + cw) = *(us8*)hv;
    }
}

// GEMM2 + fused mean-pool numerator: pooled[g,c] += relu(y2@W2+b2)[r,c]
template <int K>
__global__ __launch_bounds__(128) void gemm_relu_pool(
        const float* __restrict__ Y, const float* __restrict__ W,
        const float* __restrict__ bias, const int* __restrict__ batch,
        float* __restrict__ pooled) {
    __shared__ float As[32][132];
    __shared__ float Bs[32][68];
    __shared__ int sb[128];
    const int r0 = blockIdx.x * 128;
    const int c0 = blockIdx.y * 64;
    const int t = threadIdx.x;
    const int tx = t & 7;
    const int ty = t >> 3;
    sb[t] = batch[r0 + t];

    float acc[8][8];
#pragma unroll
    for (int i = 0; i < 8; i++)
#pragma unroll
        for (int j = 0; j < 8; j++) acc[i][j] = 0.0f;

    for (int d0 = 0; d0 < K; d0 += 32) {
        {
            const float* src = Y + (size_t)(r0 + t) * K + d0;
            float4 av[8];
#pragma unroll
            for (int q = 0; q < 8; q++) av[q] = ((const float4*)src)[q];
#pragma unroll
            for (int q = 0; q < 8; q++) {
                As[q * 4 + 0][t] = av[q].x;
                As[q * 4 + 1][t] = av[q].y;
                As[q * 4 + 2][t] = av[q].z;
                As[q * 4 + 3][t] = av[q].w;
            }
        }
        {
            int bk = t >> 2;
            int bc = (t & 3) * 16;
            const float* wsrc = W + (size_t)(d0 + bk) * 256 + c0 + bc;
#pragma unroll
            for (int q = 0; q < 4; q++) {
                float4 wvv = ((const float4*)wsrc)[q];
                *(float4*)&Bs[bk][bc + q * 4] = wvv;
            }
        }
        __syncthreads();
#pragma unroll
        for (int k = 0; k < 32; k++) {
            float a[8], b[8];
            *(float4*)&a[0] = *(const float4*)&As[k][ty * 8];
            *(float4*)&a[4] = *(const float4*)&As[k][ty * 8 + 4];
            *(float4*)&b[0] = *(const float4*)&Bs[k][tx * 8];
            *(float4*)&b[4] = *(const float4*)&Bs[k][tx * 8 + 4];
#pragma unroll
            for (int i = 0; i < 8; i++)
#pragma unroll
                for (int j = 0; j < 8; j++)
                    acc[i][j] = fmaf(a[i], b[j], acc[i][j]);
        }
        __syncthreads();
    }

    float bv[8];
#pragma unroll
    for (int j = 0; j < 8; j++) bv[j] = bias[c0 + tx * 8 + j];

    int curg = sb[ty * 8];
    float part[8];
#pragma unroll
    for (int j = 0; j < 8; j++) part[j] = 0.0f;
#pragma unroll
    for (int i = 0; i < 8; i++) {
        int g = sb[ty * 8 + i];
        if (g != curg) {
#pragma unroll
            for (int j = 0; j < 8; j++)
                atomicAdd(&pooled[curg * 256 + c0 + tx * 8 + j], part[j]);
#pragma unroll
            for (int j = 0; j < 8; j++) part[j] = 0.0f;
            curg = g;
        }
#pragma unroll
        for (int j = 0; j < 8; j++)
            part[j] += fmaxf(acc[i][j] + bv[j], 0.0f);
    }
#pragma unroll
    for (int j = 0; j < 8; j++)
        atomicAdd(&pooled[curg * 256 + c0 + tx * 8 + j], part[j]);
}

// counts per graph
__global__ void count_kernel(const int* __restrict__ batch, float* cnt) {
    __shared__ int h[GG];
    int t = threadIdx.x;
    if (t < GG) h[t] = 0;
    __syncthreads();
    int i = blockIdx.x * blockDim.x + t;
    if (i < NN) atomicAdd(&h[batch[i]], 1);
    __syncthreads();
    if (t < GG && h[t] > 0) atomicAdd(&cnt[t], (float)h[t]);
}

// out[g,c] = (pooled[g,:]/cnt[g]) . Wc[:,c] + bc[c]
__global__ void head_kernel(const float* __restrict__ pooled,
                            const float* __restrict__ cnt,
                            const float* __restrict__ Wc,
                            const float* __restrict__ bc,
                            float* __restrict__ out) {
    int g = blockIdx.x;
    int l = threadIdx.x;  // 64
    float inv = 1.0f / fmaxf(cnt[g], 1.0f);
    float acc[CDIM];
#pragma unroll
    for (int c = 0; c < CDIM; c++) acc[c] = 0.0f;
    for (int t = l; t < 256; t += 64) {
        float pv = pooled[g * 256 + t] * inv;
#pragma unroll
        for (int c = 0; c < CDIM; c++) acc[c] = fmaf(pv, Wc[t * CDIM + c], acc[c]);
    }
#pragma unroll
    for (int c = 0; c < CDIM; c++) {
        float v = acc[c];
        for (int off = 32; off > 0; off >>= 1) v += __shfl_down(v, off, 64);
        if (l == 0) out[g * CDIM + c] = v + bc[c];
    }
}

extern "C" void kernel_launch(void* const* d_in, const int* in_sizes, int n_in,
                              void* d_out, int out_size, void* d_ws, size_t ws_size,
                              hipStream_t stream) {
    const float* x  = (const float*)d_in[0];
    const int*   ei = (const int*)d_in[1];
    const int*   batch = (const int*)d_in[2];
    const float* W1 = (const float*)d_in[3];
    const float* b1 = (const float*)d_in[4];
    const float* W2 = (const float*)d_in[5];
    const float* b2 = (const float*)d_in[6];
    const float* Wc = (const float*)d_in[7];
    const float* bc = (const float*)d_in[8];
    float* out = (float*)d_out;

    char* ws = (char*)d_ws;
    unsigned* bm  = (unsigned*)(ws + OFF_BM);
    float* y1     = (float*)(ws + OFF_Y1);
    __half* h1    = (__half*)(ws + OFF_H1);
    float* y2     = (float*)(ws + OFF_Y2);
    __half* xh    = (__half*)(ws + OFF_XH);
    unsigned short* ell = (unsigned short*)(ws + OFF_ELL);
    float* dis    = (float*)(ws + OFF_DIS);
    int*   deg    = (int*)(ws + OFF_DEG);
    float* pooled = (float*)(ws + OFF_POOL);
    float* cnt    = (float*)(ws + OFF_CNT);

    // 0) x -> fp16
    cvt_f16<<<(NN * DDIM) / 1024, 256, 0, stream>>>(x, xh);
    // 1) zero 32MB bitmap + self-loop bits (fused)
    zero_selfloop<<<2048, 256, 0, stream>>>((uint4*)bm);
    // 2) edges
    edge_kernel<<<EE / 256, 256, 0, stream>>>(ei, bm);
    // 3) bitmap -> ELL(ushort) + deg + dis (wave per row)
    extract_kernel<<<(NN * 64) / 256, 256, 0, stream>>>(bm, ell, deg, dis);
    // 3b) zero pooled+cnt, counts
    zero_f<<<(GG * 256 + GG + 255) / 256, 256, 0, stream>>>(pooled, GG * 256 + GG);
    count_kernel<<<NN / 256, 256, 0, stream>>>(batch, cnt);
    // 4) SpMM1: y1 = Ahat @ xh   [N,128] fp32, 1 pass (4 MB src, L2-resident)
    {
        dim3 grid(NN, 1);
        spmm_f16<<<grid, 256, 0, stream>>>(xh, ell, deg, dis, y1, 1);
    }
    // 5) GEMM1: h1 = relu(y1 @ W1 + b1) -> fp16, 2 column planes
    {
        dim3 grid(NN / 128, 256 / 64);
        gemm_relu_f16<DDIM><<<grid, 128, 0, stream>>>(y1, W1, b1, h1);
    }
    // 6) SpMM2: y2 = Ahat @ h1  [N,256] fp32, 2 passes (4 MB plane each)
    {
        dim3 grid(NN, 2);
        spmm_f16<<<grid, 256, 0, stream>>>(h1, ell, deg, dis, y2, 2);
    }
    // 7) GEMM2 + fused pooling numerator
    {
        dim3 grid(NN / 128, 256 / 64);
        gemm_relu_pool<HDIM><<<grid, 128, 0, stream>>>(y2, W2, b2, batch, pooled);
    }
    // 8) head
    head_kernel<<<GG, 64, 0, stream>>>(pooled, cnt, Wc, bc, out);
}

// Round 6
// 262.302 us; speedup vs baseline: 1.1676x; 1.1170x over previous
//
#include <hip/hip_runtime.h>
#include <hip/hip_bf16.h>
#include <hip/hip_fp16.h>

#define NN 16384
#define EE 524288
#define DDIM 128
#define HDIM 256
#define CDIM 10
#define GG 64
#define MAXD 128
#define WPR 512   // bitmap words per row = NN/32

// workspace byte offsets (aliased; kernels are sequential on one stream)
#define OFF_BM   0ull          // 32 MB bitmap [0, 33554432), dead after extract
#define OFF_Y1   0ull          // 8 MB fp32 (alias BM, written post-extract)
#define OFF_H1   8388608ull    // 8 MB fp16, 2 planes of [NN][128] (alias BM)
#define OFF_Y2   16777216ull   // 16 MB fp32 (alias BM tail)
#define OFF_XH   33554432ull   // 4 MB fp16 x (disjoint from BM)
#define OFF_ELL  37748736ull   // 4 MB ushort ELL
#define OFF_DIS  41943040ull   // 64 KB
#define OFF_DEG  42008576ull   // 64 KB
#define OFF_POOL 42074112ull   // 64 KB (16384 floats)
#define OFF_CNT  42139648ull   // 256 B (64 floats, contiguous after POOL)

__global__ void cvt_f16(const float* __restrict__ in, __half* __restrict__ out) {
    int i = (blockIdx.x * blockDim.x + threadIdx.x) * 4;
    float4 v = *(const float4*)(in + i);
    __half2 a = __floats2half2_rn(v.x, v.y);
    __half2 b = __floats2half2_rn(v.z, v.w);
    *(__half2*)(out + i)     = a;
    *(__half2*)(out + i + 2) = b;
}

// zero the bitmap AND plant the self-loop bits in one pass
__global__ void zero_selfloop(uint4* p) {
    int i = blockIdx.x * blockDim.x + threadIdx.x;
    int stride = gridDim.x * blockDim.x;
    const int n16 = NN * WPR / 4;  // 2M uint4
    for (; i < n16; i += stride) {
        uint4 z = make_uint4(0u, 0u, 0u, 0u);
        int r = i >> 7;       // row (128 uint4 slots per row)
        int slot = i & 127;   // which uint4 within the row
        int sw = r >> 5;      // self word index within row
        if ((sw >> 2) == slot) {
            unsigned bit = 1u << (r & 31);
            int comp = sw & 3;
            if (comp == 0) z.x = bit;
            else if (comp == 1) z.y = bit;
            else if (comp == 2) z.z = bit;
            else z.w = bit;
        }
        p[i] = z;
    }
}

__global__ void zero_f(float* p, int n) {
    int i = blockIdx.x * blockDim.x + threadIdx.x;
    if (i < n) p[i] = 0.0f;
}

__global__ void edge_kernel(const int* __restrict__ ei, unsigned* bm) {
    int e = blockIdx.x * blockDim.x + threadIdx.x;
    if (e < EE) {
        int s = ei[e];
        int d = ei[EE + e];
        atomicOr(&bm[s * WPR + (d >> 5)], 1u << (d & 31));
    }
}

// one wave per row: popcount + prefix scan -> ELL cols (ushort), deg, dis
__global__ void extract_kernel(const unsigned* __restrict__ bm,
                               unsigned short* __restrict__ ell, int* __restrict__ deg,
                               float* __restrict__ dis) {
    int gtid = blockIdx.x * blockDim.x + threadIdx.x;
    int row  = gtid >> 6;
    int lane = threadIdx.x & 63;
    if (row >= NN) return;
    const uint4* wp = (const uint4*)(bm + (size_t)row * WPR + lane * 8);
    uint4 a = wp[0];
    uint4 b = wp[1];
    unsigned w[8] = {a.x, a.y, a.z, a.w, b.x, b.y, b.z, b.w};
    int pc = 0;
#pragma unroll
    for (int k = 0; k < 8; k++) pc += __popc(w[k]);
    int pre = pc;
#pragma unroll
    for (int off = 1; off < 64; off <<= 1) {
        int o = __shfl_up(pre, off, 64);
        if (lane >= off) pre += o;
    }
    int total = __shfl(pre, 63, 64);
    pre -= pc;  // exclusive
    int base = row * MAXD;
    int pos = pre;
#pragma unroll
    for (int k = 0; k < 8; k++) {
        unsigned bits = w[k];
        int cbase = lane * 256 + k * 32;
        while (bits) {
            int bit = __ffs(bits) - 1;
            if (pos < MAXD) ell[base + pos] = (unsigned short)(cbase + bit);
            pos++;
            bits &= bits - 1;
        }
    }
    if (lane == 0) {
        deg[row] = total < MAXD ? total : MAXD;
        dis[row] = 1.0f / sqrtf((float)total);
    }
}

// y[row, p*128+t] = dis[row] * sum_k dis[c_k] * src[p][c_k][t]
// src: [P][NN][128] fp16 planes (each 4 MB -> per-XCD L2 resident per pass).
__global__ __launch_bounds__(256) void spmm_f16(const __half* __restrict__ src,
                                                const unsigned short* __restrict__ ell,
                                                const int* __restrict__ deg,
                                                const float* __restrict__ dis,
                                                float* __restrict__ y, int P) {
    __shared__ int2  scw[MAXD];
    __shared__ float red[4][128];
    const int row  = blockIdx.x;
    const int p    = blockIdx.y;
    const int t    = threadIdx.x;
    const int wv   = t >> 6;
    const int lane = t & 63;
    const int d    = deg[row];
    if (t < d) {
        int c = ell[row * MAXD + t];
        scw[t] = make_int2(c, __float_as_int(dis[c]));
    }
    __syncthreads();

    const __half* plane = src + (size_t)p * NN * 128;
    float a0 = 0.0f, a1 = 0.0f;
#pragma unroll 2
    for (int k = wv; k < d; k += 4) {
        int2 pr = scw[k];
        float wgt = __int_as_float(pr.y);
        __half2 h = *(const __half2*)(plane + (size_t)pr.x * 128 + lane * 2);
        float2 f = __half22float2(h);
        a0 = fmaf(wgt, f.x, a0);
        a1 = fmaf(wgt, f.y, a1);
    }
    *(float2*)&red[wv][lane * 2] = make_float2(a0, a1);
    __syncthreads();
    if (t < 128) {
        float s = red[0][t] + red[1][t] + red[2][t] + red[3][t];
        y[(size_t)row * (P * 128) + p * 128 + t] = dis[row] * s;
    }
}

// ---- shared GEMM body pieces: 64x64 tile, 256 threads, 4x4 micro ----
// As[k][row], Bs[k][col], k-chunk 32. Stride 68 floats (272B, 16B-aligned).

#define GEMM_STAGE(Y, W, K)                                                    \
    {                                                                          \
        const float* src = Y + (size_t)(r0 + (t >> 2)) * K + d0 + (t & 3) * 8; \
        float4 a0 = ((const float4*)src)[0];                                   \
        float4 a1 = ((const float4*)src)[1];                                   \
        int kq = (t & 3) * 8, rr = t >> 2;                                     \
        As[kq + 0][rr] = a0.x; As[kq + 1][rr] = a0.y;                          \
        As[kq + 2][rr] = a0.z; As[kq + 3][rr] = a0.w;                          \
        As[kq + 4][rr] = a1.x; As[kq + 5][rr] = a1.y;                          \
        As[kq + 6][rr] = a1.z; As[kq + 7][rr] = a1.w;                          \
        const float* wsrc = W + (size_t)(d0 + (t >> 3)) * 256 + c0 + (t & 7) * 8; \
        float4 b0 = ((const float4*)wsrc)[0];                                  \
        float4 b1 = ((const float4*)wsrc)[1];                                  \
        *(float4*)&Bs[t >> 3][(t & 7) * 8]     = b0;                           \
        *(float4*)&Bs[t >> 3][(t & 7) * 8 + 4] = b1;                           \
    }

#define GEMM_INNER                                                             \
    _Pragma("unroll")                                                          \
    for (int k = 0; k < 32; k++) {                                             \
        float4 av = *(const float4*)&As[k][ty * 4];                            \
        float4 bv4 = *(const float4*)&Bs[k][tx * 4];                           \
        float a[4] = {av.x, av.y, av.z, av.w};                                 \
        float b[4] = {bv4.x, bv4.y, bv4.z, bv4.w};                             \
        _Pragma("unroll")                                                      \
        for (int i = 0; i < 4; i++)                                            \
            _Pragma("unroll")                                                  \
            for (int j = 0; j < 4; j++)                                        \
                acc[i][j] = fmaf(a[i], b[j], acc[i][j]);                       \
    }

// GEMM1: H = relu(Y @ W + b) -> fp16, 2 column planes [2][NN][128]
template <int K>
__global__ __launch_bounds__(256) void gemm_relu_f16(
        const float* __restrict__ Y, const float* __restrict__ W,
        const float* __restrict__ bias, __half* __restrict__ H) {
    __shared__ float As[32][68];
    __shared__ float Bs[32][68];
    const int r0 = blockIdx.x * 64;
    const int c0 = blockIdx.y * 64;
    const int t = threadIdx.x;
    const int tx = t & 15;
    const int ty = t >> 4;

    float acc[4][4];
#pragma unroll
    for (int i = 0; i < 4; i++)
#pragma unroll
        for (int j = 0; j < 4; j++) acc[i][j] = 0.0f;

    for (int d0 = 0; d0 < K; d0 += 32) {
        GEMM_STAGE(Y, W, K)
        __syncthreads();
        GEMM_INNER
        __syncthreads();
    }

    float bv[4];
#pragma unroll
    for (int j = 0; j < 4; j++) bv[j] = bias[c0 + tx * 4 + j];
    const int cbase = c0 + tx * 4;
    const int pl = cbase >> 7;
    const int cw = cbase & 127;
#pragma unroll
    for (int i = 0; i < 4; i++) {
        __half hv[4];
#pragma unroll
        for (int j = 0; j < 4; j++) hv[j] = __float2half(fmaxf(acc[i][j] + bv[j], 0.0f));
        *(ushort4*)(H + (size_t)pl * NN * 128 + (size_t)(r0 + ty * 4 + i) * 128 + cw) =
            *(ushort4*)hv;
    }
}

// GEMM2 + fused mean-pool numerator via LDS pool tile.
// 64-row window of sorted batch spans <= NG graphs (avg 256 nodes/graph).
#define NG 8
template <int K>
__global__ __launch_bounds__(256) void gemm_relu_pool(
        const float* __restrict__ Y, const float* __restrict__ W,
        const float* __restrict__ bias, const int* __restrict__ batch,
        float* __restrict__ pooled) {
    __shared__ float As[32][68];
    __shared__ float Bs[32][68];
    __shared__ float pools[NG][68];
    __shared__ int sb[64];
    const int r0 = blockIdx.x * 64;
    const int c0 = blockIdx.y * 64;
    const int t = threadIdx.x;
    const int tx = t & 15;
    const int ty = t >> 4;
    if (t < 64) sb[t] = batch[r0 + t];
    for (int i = t; i < NG * 68; i += 256) ((float*)pools)[i] = 0.0f;

    float acc[4][4];
#pragma unroll
    for (int i = 0; i < 4; i++)
#pragma unroll
        for (int j = 0; j < 4; j++) acc[i][j] = 0.0f;

    for (int d0 = 0; d0 < K; d0 += 32) {
        GEMM_STAGE(Y, W, K)
        __syncthreads();
        GEMM_INNER
        __syncthreads();
    }

    float bv[4];
#pragma unroll
    for (int j = 0; j < 4; j++) bv[j] = bias[c0 + tx * 4 + j];

    const int g0 = sb[0];
    const int ng = min(sb[63] - g0 + 1, NG);
#pragma unroll
    for (int i = 0; i < 4; i++) {
        int gi = min(sb[ty * 4 + i] - g0, NG - 1);
#pragma unroll
        for (int j = 0; j < 4; j++) {
            float v = fmaxf(acc[i][j] + bv[j], 0.0f);
            atomicAdd(&pools[gi][tx * 4 + j], v);
        }
    }
    __syncthreads();
    for (int i = t; i < ng * 64; i += 256) {
        int gi = i >> 6, c = i & 63;
        float v = pools[gi][c];
        if (v != 0.0f) atomicAdd(&pooled[(g0 + gi) * 256 + c0 + c], v);
    }
}

// counts per graph
__global__ void count_kernel(const int* __restrict__ batch, float* cnt) {
    __shared__ int h[GG];
    int t = threadIdx.x;
    if (t < GG) h[t] = 0;
    __syncthreads();
    int i = blockIdx.x * blockDim.x + t;
    if (i < NN) atomicAdd(&h[batch[i]], 1);
    __syncthreads();
    if (t < GG && h[t] > 0) atomicAdd(&cnt[t], (float)h[t]);
}

// out[g,c] = (pooled[g,:]/cnt[g]) . Wc[:,c] + bc[c]
__global__ void head_kernel(const float* __restrict__ pooled,
                            const float* __restrict__ cnt,
                            const float* __restrict__ Wc,
                            const float* __restrict__ bc,
                            float* __restrict__ out) {
    int g = blockIdx.x;
    int l = threadIdx.x;  // 64
    float inv = 1.0f / fmaxf(cnt[g], 1.0f);
    float acc[CDIM];
#pragma unroll
    for (int c = 0; c < CDIM; c++) acc[c] = 0.0f;
    for (int t = l; t < 256; t += 64) {
        float pv = pooled[g * 256 + t] * inv;
#pragma unroll
        for (int c = 0; c < CDIM; c++) acc[c] = fmaf(pv, Wc[t * CDIM + c], acc[c]);
    }
#pragma unroll
    for (int c = 0; c < CDIM; c++) {
        float v = acc[c];
        for (int off = 32; off > 0; off >>= 1) v += __shfl_down(v, off, 64);
        if (l == 0) out[g * CDIM + c] = v + bc[c];
    }
}

extern "C" void kernel_launch(void* const* d_in, const int* in_sizes, int n_in,
                              void* d_out, int out_size, void* d_ws, size_t ws_size,
                              hipStream_t stream) {
    const float* x  = (const float*)d_in[0];
    const int*   ei = (const int*)d_in[1];
    const int*   batch = (const int*)d_in[2];
    const float* W1 = (const float*)d_in[3];
    const float* b1 = (const float*)d_in[4];
    const float* W2 = (const float*)d_in[5];
    const float* b2 = (const float*)d_in[6];
    const float* Wc = (const float*)d_in[7];
    const float* bc = (const float*)d_in[8];
    float* out = (float*)d_out;

    char* ws = (char*)d_ws;
    unsigned* bm  = (unsigned*)(ws + OFF_BM);
    float* y1     = (float*)(ws + OFF_Y1);
    __half* h1    = (__half*)(ws + OFF_H1);
    float* y2     = (float*)(ws + OFF_Y2);
    __half* xh    = (__half*)(ws + OFF_XH);
    unsigned short* ell = (unsigned short*)(ws + OFF_ELL);
    float* dis    = (float*)(ws + OFF_DIS);
    int*   deg    = (int*)(ws + OFF_DEG);
    float* pooled = (float*)(ws + OFF_POOL);
    float* cnt    = (float*)(ws + OFF_CNT);

    // 0) x -> fp16
    cvt_f16<<<(NN * DDIM) / 1024, 256, 0, stream>>>(x, xh);
    // 1) zero 32MB bitmap + self-loop bits (fused)
    zero_selfloop<<<2048, 256, 0, stream>>>((uint4*)bm);
    // 2) edges
    edge_kernel<<<EE / 256, 256, 0, stream>>>(ei, bm);
    // 3) bitmap -> ELL(ushort) + deg + dis (wave per row)
    extract_kernel<<<(NN * 64) / 256, 256, 0, stream>>>(bm, ell, deg, dis);
    // 3b) zero pooled+cnt, counts
    zero_f<<<(GG * 256 + GG + 255) / 256, 256, 0, stream>>>(pooled, GG * 256 + GG);
    count_kernel<<<NN / 256, 256, 0, stream>>>(batch, cnt);
    // 4) SpMM1: y1 = Ahat @ xh   [N,128] fp32 (4 MB src, L2-resident)
    {
        dim3 grid(NN, 1);
        spmm_f16<<<grid, 256, 0, stream>>>(xh, ell, deg, dis, y1, 1);
    }
    // 5) GEMM1: h1 = relu(y1 @ W1 + b1) -> fp16, 2 column planes
    {
        dim3 grid(NN / 64, 256 / 64);
        gemm_relu_f16<DDIM><<<grid, 256, 0, stream>>>(y1, W1, b1, h1);
    }
    // 6) SpMM2: y2 = Ahat @ h1  [N,256] fp32, 2 passes (4 MB plane each)
    {
        dim3 grid(NN, 2);
        spmm_f16<<<grid, 256, 0, stream>>>(h1, ell, deg, dis, y2, 2);
    }
    // 7) GEMM2 + fused pooling numerator
    {
        dim3 grid(NN / 64, 256 / 64);
        gemm_relu_pool<HDIM><<<grid, 256, 0, stream>>>(y2, W2, b2, batch, pooled);
    }
    // 8) head
    head_kernel<<<GG, 64, 0, stream>>>(pooled, cnt, Wc, bc, out);
}

// Round 7
// 236.195 us; speedup vs baseline: 1.2966x; 1.1105x over previous
//
#include <hip/hip_runtime.h>
#include <hip/hip_bf16.h>
#include <hip/hip_fp16.h>

#define NN 16384
#define EE 524288
#define DDIM 128
#define HDIM 256
#define CDIM 10
#define GG 64
#define MAXD 128
#define WPR 512   // bitmap words per row = NN/32

typedef _Float16 h8 __attribute__((ext_vector_type(8)));
typedef float f4 __attribute__((ext_vector_type(4)));
typedef unsigned short su8 __attribute__((ext_vector_type(8)));

// workspace byte offsets (aliased; kernels are sequential on one stream)
#define OFF_BM   0ull          // 32 MB bitmap [0, 33554432), dead after extract
#define OFF_Y1H  0ull          // 4 MB fp16 [NN][128] (alias BM, post-extract)
#define OFF_H1   8388608ull    // 8 MB fp16, 2 planes [NN][128] (alias BM)
#define OFF_Y2H  16777216ull   // 8 MB fp16 [NN][256] (alias BM tail)
#define OFF_XH   33554432ull   // 4 MB fp16 x
#define OFF_ELL  37748736ull   // 4 MB ushort ELL
#define OFF_DIS  41943040ull   // 64 KB
#define OFF_DEG  42008576ull   // 64 KB
#define OFF_POOL 42074112ull   // 64 KB (16384 floats)
#define OFF_CNT  42139648ull   // 64 KB slot (64 floats, right after POOL)
#define OFF_WT1  42205184ull   // 64 KB fp16 Wt1[256][128]
#define OFF_WT2  42270720ull   // 128 KB fp16 Wt2[256][256]

__global__ void cvt_f16(const float* __restrict__ in, _Float16* __restrict__ out) {
    int i = (blockIdx.x * blockDim.x + threadIdx.x) * 4;
    float4 v = *(const float4*)(in + i);
    _Float16 o[4] = {(_Float16)v.x, (_Float16)v.y, (_Float16)v.z, (_Float16)v.w};
    *(ushort4*)(out + i) = *(ushort4*)o;
}

// Wt[n][k] = (fp16) W[k][n];  W is [K,256]
__global__ void cvt_wt(const float* __restrict__ W, _Float16* __restrict__ Wt, int K) {
    int i = blockIdx.x * 256 + threadIdx.x;  // over 256*K
    int n = i / K, k = i - n * K;
    Wt[i] = (_Float16)W[k * 256 + n];
}

// zero the bitmap AND plant the self-loop bits in one pass
__global__ void zero_selfloop(uint4* p) {
    int i = blockIdx.x * blockDim.x + threadIdx.x;
    int stride = gridDim.x * blockDim.x;
    const int n16 = NN * WPR / 4;  // 2M uint4
    for (; i < n16; i += stride) {
        uint4 z = make_uint4(0u, 0u, 0u, 0u);
        int r = i >> 7;
        int slot = i & 127;
        int sw = r >> 5;
        if ((sw >> 2) == slot) {
            unsigned bit = 1u << (r & 31);
            int comp = sw & 3;
            if (comp == 0) z.x = bit;
            else if (comp == 1) z.y = bit;
            else if (comp == 2) z.z = bit;
            else z.w = bit;
        }
        p[i] = z;
    }
}

__global__ void zero_f(float* p, int n) {
    int i = blockIdx.x * blockDim.x + threadIdx.x;
    if (i < n) p[i] = 0.0f;
}

__global__ void edge_kernel(const int* __restrict__ ei, unsigned* bm) {
    int e = blockIdx.x * blockDim.x + threadIdx.x;
    if (e < EE) {
        int s = ei[e];
        int d = ei[EE + e];
        atomicOr(&bm[s * WPR + (d >> 5)], 1u << (d & 31));
    }
}

// one wave per row: popcount + prefix scan -> ELL cols (ushort), deg, dis
__global__ void extract_kernel(const unsigned* __restrict__ bm,
                               unsigned short* __restrict__ ell, int* __restrict__ deg,
                               float* __restrict__ dis) {
    int gtid = blockIdx.x * blockDim.x + threadIdx.x;
    int row  = gtid >> 6;
    int lane = threadIdx.x & 63;
    if (row >= NN) return;
    const uint4* wp = (const uint4*)(bm + (size_t)row * WPR + lane * 8);
    uint4 a = wp[0];
    uint4 b = wp[1];
    unsigned w[8] = {a.x, a.y, a.z, a.w, b.x, b.y, b.z, b.w};
    int pc = 0;
#pragma unroll
    for (int k = 0; k < 8; k++) pc += __popc(w[k]);
    int pre = pc;
#pragma unroll
    for (int off = 1; off < 64; off <<= 1) {
        int o = __shfl_up(pre, off, 64);
        if (lane >= off) pre += o;
    }
    int total = __shfl(pre, 63, 64);
    pre -= pc;  // exclusive
    int base = row * MAXD;
    int pos = pre;
#pragma unroll
    for (int k = 0; k < 8; k++) {
        unsigned bits = w[k];
        int cbase = lane * 256 + k * 32;
        while (bits) {
            int bit = __ffs(bits) - 1;
            if (pos < MAXD) ell[base + pos] = (unsigned short)(cbase + bit);
            pos++;
            bits &= bits - 1;
        }
    }
    if (lane == 0) {
        deg[row] = total < MAXD ? total : MAXD;
        dis[row] = 1.0f / sqrtf((float)total);
    }
}

// y[row, p*128+t] = (fp16)(dis[row] * sum_k dis[c_k] * src[p][c_k][t])
// src: [P][NN][128] fp16 planes (4 MB each -> per-XCD L2 resident per pass).
__global__ __launch_bounds__(256) void spmm_f16(const _Float16* __restrict__ src,
                                                const unsigned short* __restrict__ ell,
                                                const int* __restrict__ deg,
                                                const float* __restrict__ dis,
                                                _Float16* __restrict__ y, int P) {
    __shared__ int2  scw[MAXD];
    __shared__ float red[4][128];
    const int row  = blockIdx.x;
    const int p    = blockIdx.y;
    const int t    = threadIdx.x;
    const int wv   = t >> 6;
    const int lane = t & 63;
    const int d    = deg[row];
    if (t < d) {
        int c = ell[row * MAXD + t];
        scw[t] = make_int2(c, __float_as_int(dis[c]));
    }
    __syncthreads();

    const _Float16* plane = src + (size_t)p * NN * 128;
    float a0 = 0.0f, a1 = 0.0f;
#pragma unroll 2
    for (int k = wv; k < d; k += 4) {
        int2 pr = scw[k];
        float wgt = __int_as_float(pr.y);
        ushort2 u = *(const ushort2*)(plane + (size_t)pr.x * 128 + lane * 2);
        _Float16 f0 = *(_Float16*)&u.x, f1 = *(_Float16*)&u.y;
        a0 = fmaf(wgt, (float)f0, a0);
        a1 = fmaf(wgt, (float)f1, a1);
    }
    *(float2*)&red[wv][lane * 2] = make_float2(a0, a1);
    __syncthreads();
    if (t < 128) {
        float s = red[0][t] + red[1][t] + red[2][t] + red[3][t];
        y[(size_t)row * (P * 128) + p * 128 + t] = (_Float16)(dis[row] * s);
    }
}

// ================= MFMA GEMM: 128x64 tile, 256 thr / 4 waves ================
// A:[M,K] fp16 row-major. Bt:[256][K] fp16 (pre-transposed W). K-chunk 32.
// Wave (wm,wn): 4 m-tiles x 2 n-tiles of 16x16x32 MFMA.
#define ASTR 40   // f16 stride (80 B, 16B-aligned)
#define BSTR 40

#define MFMA_PROLOG                                                            \
    const int r0 = blockIdx.x * 128;                                           \
    const int c0 = blockIdx.y * 64;                                            \
    const int t = threadIdx.x;                                                 \
    const int lane = t & 63, wv = t >> 6;                                      \
    const int wm = wv >> 1, wn = wv & 1;                                       \
    const int qm = lane & 15, qk = lane >> 4;                                  \
    f4 acc[4][2];                                                              \
    _Pragma("unroll") for (int i = 0; i < 4; i++)                              \
        _Pragma("unroll") for (int j = 0; j < 2; j++)                          \
            acc[i][j] = (f4){0.f, 0.f, 0.f, 0.f};

#define MFMA_KLOOP(Aptr, Wtptr, K)                                             \
    for (int k0 = 0; k0 < K; k0 += 32) {                                       \
        __syncthreads();                                                       \
        {                                                                      \
            int r = t >> 1, ko = (t & 1) * 16;                                 \
            const su8* srcA = (const su8*)(Aptr + (size_t)(r0 + r) * K + k0 + ko); \
            su8 a0 = srcA[0], a1 = srcA[1];                                    \
            *(su8*)&As[r * ASTR + ko]     = a0;                                \
            *(su8*)&As[r * ASTR + ko + 8] = a1;                                \
            int n = t >> 2, ko2 = (t & 3) * 8;                                 \
            *(su8*)&Bs[n * BSTR + ko2] =                                       \
                *(const su8*)(Wtptr + (size_t)(c0 + n) * K + k0 + ko2);        \
        }                                                                      \
        __syncthreads();                                                       \
        h8 bfr[2];                                                             \
        _Pragma("unroll") for (int j = 0; j < 2; j++)                          \
            bfr[j] = *(const h8*)&Bs[(wn * 32 + j * 16 + qm) * BSTR + qk * 8]; \
        _Pragma("unroll") for (int i = 0; i < 4; i++) {                        \
            h8 afr = *(const h8*)&As[(wm * 64 + i * 16 + qm) * ASTR + qk * 8]; \
            _Pragma("unroll") for (int j = 0; j < 2; j++)                      \
                acc[i][j] = __builtin_amdgcn_mfma_f32_16x16x32_f16(            \
                    afr, bfr[j], acc[i][j], 0, 0, 0);                          \
        }                                                                      \
    }

// GEMM1: h1 = relu(y1 @ W1 + b1) -> fp16, 2 column planes [2][NN][128]
template <int K>
__global__ __launch_bounds__(256) void gemm_mfma_f16(
        const _Float16* __restrict__ A, const _Float16* __restrict__ Wt,
        const float* __restrict__ bias, _Float16* __restrict__ H) {
    __shared__ __align__(16) _Float16 As[128 * ASTR];
    __shared__ __align__(16) _Float16 Bs[64 * BSTR];
    __shared__ __align__(16) _Float16 Cs[128 * 72];
    MFMA_PROLOG
    MFMA_KLOOP(A, Wt, K)

    float bv[2];
#pragma unroll
    for (int j = 0; j < 2; j++) bv[j] = bias[c0 + wn * 32 + j * 16 + qm];
#pragma unroll
    for (int i = 0; i < 4; i++)
#pragma unroll
        for (int j = 0; j < 2; j++) {
            int lc = wn * 32 + j * 16 + qm;
#pragma unroll
            for (int rr = 0; rr < 4; rr++) {
                int lr = wm * 64 + i * 16 + qk * 4 + rr;
                Cs[lr * 72 + lc] = (_Float16)fmaxf(acc[i][j][rr] + bv[j], 0.0f);
            }
        }
    __syncthreads();
    // coalesced store: thread t -> row t>>1, 32 f16 half-row
    {
        int r = t >> 1, half_ = t & 1;
        const int pl = c0 >> 7;
        const int cw = (c0 & 127) + half_ * 32;
        _Float16* dst = H + (size_t)pl * NN * 128 + (size_t)(r0 + r) * 128 + cw;
        const _Float16* srcc = &Cs[r * 72 + half_ * 32];
#pragma unroll
        for (int q = 0; q < 4; q++)
            *(su8*)(dst + q * 8) = *(const su8*)(srcc + q * 8);
    }
}

// GEMM2 + fused mean-pool numerator (no C materialization).
#define NG 8
template <int K>
__global__ __launch_bounds__(256) void gemm_mfma_pool(
        const _Float16* __restrict__ A, const _Float16* __restrict__ Wt,
        const float* __restrict__ bias, const int* __restrict__ batch,
        float* __restrict__ pooled) {
    __shared__ __align__(16) _Float16 As[128 * ASTR];
    __shared__ __align__(16) _Float16 Bs[64 * BSTR];
    __shared__ float pools[NG][68];
    __shared__ int sb[128];
    MFMA_PROLOG
    if (t < 128) sb[t] = batch[r0 + t];
    for (int i = t; i < NG * 68; i += 256) ((float*)pools)[i] = 0.0f;
    MFMA_KLOOP(A, Wt, K)

    float bv[2];
#pragma unroll
    for (int j = 0; j < 2; j++) bv[j] = bias[c0 + wn * 32 + j * 16 + qm];
    __syncthreads();  // pools/sb ready (also covers last K-chunk LDS reuse)
    const int g0 = sb[0];
#pragma unroll
    for (int i = 0; i < 4; i++)
#pragma unroll
        for (int j = 0; j < 2; j++) {
            int lc = wn * 32 + j * 16 + qm;
#pragma unroll
            for (int rr = 0; rr < 4; rr++) {
                int lr = wm * 64 + i * 16 + qk * 4 + rr;
                int gi = min(sb[lr] - g0, NG - 1);
                float v = fmaxf(acc[i][j][rr] + bv[j], 0.0f);
                atomicAdd(&pools[gi][lc], v);
            }
        }
    __syncthreads();
    const int ng = min(sb[127] - g0 + 1, NG);
    for (int i2 = t; i2 < ng * 64; i2 += 256) {
        int gi = i2 >> 6, c = i2 & 63;
        float v = pools[gi][c];
        if (v != 0.0f) atomicAdd(&pooled[(g0 + gi) * 256 + c0 + c], v);
    }
}

// counts per graph
__global__ void count_kernel(const int* __restrict__ batch, float* cnt) {
    __shared__ int h[GG];
    int t = threadIdx.x;
    if (t < GG) h[t] = 0;
    __syncthreads();
    int i = blockIdx.x * blockDim.x + t;
    if (i < NN) atomicAdd(&h[batch[i]], 1);
    __syncthreads();
    if (t < GG && h[t] > 0) atomicAdd(&cnt[t], (float)h[t]);
}

// out[g,c] = (pooled[g,:]/cnt[g]) . Wc[:,c] + bc[c]
__global__ void head_kernel(const float* __restrict__ pooled,
                            const float* __restrict__ cnt,
                            const float* __restrict__ Wc,
                            const float* __restrict__ bc,
                            float* __restrict__ out) {
    int g = blockIdx.x;
    int l = threadIdx.x;  // 64
    float inv = 1.0f / fmaxf(cnt[g], 1.0f);
    float acc[CDIM];
#pragma unroll
    for (int c = 0; c < CDIM; c++) acc[c] = 0.0f;
    for (int t = l; t < 256; t += 64) {
        float pv = pooled[g * 256 + t] * inv;
#pragma unroll
        for (int c = 0; c < CDIM; c++) acc[c] = fmaf(pv, Wc[t * CDIM + c], acc[c]);
    }
#pragma unroll
    for (int c = 0; c < CDIM; c++) {
        float v = acc[c];
        for (int off = 32; off > 0; off >>= 1) v += __shfl_down(v, off, 64);
        if (l == 0) out[g * CDIM + c] = v + bc[c];
    }
}

extern "C" void kernel_launch(void* const* d_in, const int* in_sizes, int n_in,
                              void* d_out, int out_size, void* d_ws, size_t ws_size,
                              hipStream_t stream) {
    const float* x  = (const float*)d_in[0];
    const int*   ei = (const int*)d_in[1];
    const int*   batch = (const int*)d_in[2];
    const float* W1 = (const float*)d_in[3];
    const float* b1 = (const float*)d_in[4];
    const float* W2 = (const float*)d_in[5];
    const float* b2 = (const float*)d_in[6];
    const float* Wc = (const float*)d_in[7];
    const float* bc = (const float*)d_in[8];
    float* out = (float*)d_out;

    char* ws = (char*)d_ws;
    unsigned* bm   = (unsigned*)(ws + OFF_BM);
    _Float16* y1h  = (_Float16*)(ws + OFF_Y1H);
    _Float16* h1   = (_Float16*)(ws + OFF_H1);
    _Float16* y2h  = (_Float16*)(ws + OFF_Y2H);
    _Float16* xh   = (_Float16*)(ws + OFF_XH);
    unsigned short* ell = (unsigned short*)(ws + OFF_ELL);
    float* dis     = (float*)(ws + OFF_DIS);
    int*   deg     = (int*)(ws + OFF_DEG);
    float* pooled  = (float*)(ws + OFF_POOL);
    float* cnt     = (float*)(ws + OFF_CNT);
    _Float16* wt1  = (_Float16*)(ws + OFF_WT1);
    _Float16* wt2  = (_Float16*)(ws + OFF_WT2);

    // 0) conversions: x -> fp16; W1,W2 -> fp16 transposed
    cvt_f16<<<(NN * DDIM) / 1024, 256, 0, stream>>>(x, xh);
    cvt_wt<<<(256 * DDIM) / 256, 256, 0, stream>>>(W1, wt1, DDIM);
    cvt_wt<<<(256 * HDIM) / 256, 256, 0, stream>>>(W2, wt2, HDIM);
    // 1) zero 32MB bitmap + self-loop bits (fused)
    zero_selfloop<<<2048, 256, 0, stream>>>((uint4*)bm);
    // 2) edges
    edge_kernel<<<EE / 256, 256, 0, stream>>>(ei, bm);
    // 3) bitmap -> ELL(ushort) + deg + dis (wave per row)
    extract_kernel<<<(NN * 64) / 256, 256, 0, stream>>>(bm, ell, deg, dis);
    // 3b) zero pooled+cnt, counts
    zero_f<<<(GG * 256 + GG + 255) / 256, 256, 0, stream>>>(pooled, GG * 256 + GG);
    count_kernel<<<NN / 256, 256, 0, stream>>>(batch, cnt);
    // 4) SpMM1: y1h = Ahat @ xh   [N,128] fp16 (4 MB src, L2-resident)
    {
        dim3 grid(NN, 1);
        spmm_f16<<<grid, 256, 0, stream>>>(xh, ell, deg, dis, y1h, 1);
    }
    // 5) GEMM1 (MFMA): h1 = relu(y1h @ W1 + b1) -> fp16, 2 column planes
    {
        dim3 grid(NN / 128, 256 / 64);
        gemm_mfma_f16<DDIM><<<grid, 256, 0, stream>>>(y1h, wt1, b1, h1);
    }
    // 6) SpMM2: y2h = Ahat @ h1  [N,256] fp16, 2 passes (4 MB plane each)
    {
        dim3 grid(NN, 2);
        spmm_f16<<<grid, 256, 0, stream>>>(h1, ell, deg, dis, y2h, 2);
    }
    // 7) GEMM2 (MFMA) + fused pooling numerator
    {
        dim3 grid(NN / 128, 256 / 64);
        gemm_mfma_pool<HDIM><<<grid, 256, 0, stream>>>(y2h, wt2, b2, batch, pooled);
    }
    // 8) head
    head_kernel<<<GG, 64, 0, stream>>>(pooled, cnt, Wc, bc, out);
}

// Round 8
// 226.897 us; speedup vs baseline: 1.3498x; 1.0410x over previous
//
#include <hip/hip_runtime.h>
#include <hip/hip_bf16.h>
#include <hip/hip_fp16.h>

#define NN 16384
#define EE 524288
#define DDIM 128
#define HDIM 256
#define CDIM 10
#define GG 64
#define MAXD 128
#define WPR 512   // bitmap words per row = NN/32

typedef _Float16 h8 __attribute__((ext_vector_type(8)));
typedef float f4 __attribute__((ext_vector_type(4)));
typedef unsigned short su8 __attribute__((ext_vector_type(8)));

// workspace byte offsets (aliased; kernels are sequential on one stream)
#define OFF_BM   0ull          // 32 MB bitmap [0, 33554432), dead after extract
#define OFF_Y1H  0ull          // 4 MB fp16 [NN][128] (alias BM, post-extract)
#define OFF_H1   8388608ull    // 8 MB fp16, 2 planes [NN][128] (alias BM)
#define OFF_Y2H  16777216ull   // 8 MB fp16 [NN][256] (alias BM tail)
#define OFF_XH   33554432ull   // 4 MB fp16 x
#define OFF_ELL  37748736ull   // 4 MB ushort ELL
#define OFF_DIS  41943040ull   // 64 KB
#define OFF_DEG  42008576ull   // 64 KB
#define OFF_POOL 42074112ull   // 64 KB (16384 floats)
#define OFF_CNT  42139648ull   // 64 KB slot (64 floats, right after POOL)
#define OFF_WT1  42205184ull   // 64 KB fp16 Wt1[256][128]
#define OFF_WT2  42270720ull   // 128 KB fp16 Wt2[256][256]

__global__ void cvt_f16(const float* __restrict__ in, _Float16* __restrict__ out) {
    int i = (blockIdx.x * blockDim.x + threadIdx.x) * 4;
    float4 v = *(const float4*)(in + i);
    _Float16 o[4] = {(_Float16)v.x, (_Float16)v.y, (_Float16)v.z, (_Float16)v.w};
    *(ushort4*)(out + i) = *(ushort4*)o;
}

// Wt[n][k] = (fp16) W[k][n];  W is [K,256]
__global__ void cvt_wt(const float* __restrict__ W, _Float16* __restrict__ Wt, int K) {
    int i = blockIdx.x * 256 + threadIdx.x;  // over 256*K
    int n = i / K, k = i - n * K;
    Wt[i] = (_Float16)W[k * 256 + n];
}

// zero the bitmap AND plant the self-loop bits in one pass
__global__ void zero_selfloop(uint4* p) {
    int i = blockIdx.x * blockDim.x + threadIdx.x;
    int stride = gridDim.x * blockDim.x;
    const int n16 = NN * WPR / 4;  // 2M uint4
    for (; i < n16; i += stride) {
        uint4 z = make_uint4(0u, 0u, 0u, 0u);
        int r = i >> 7;
        int slot = i & 127;
        int sw = r >> 5;
        if ((sw >> 2) == slot) {
            unsigned bit = 1u << (r & 31);
            int comp = sw & 3;
            if (comp == 0) z.x = bit;
            else if (comp == 1) z.y = bit;
            else if (comp == 2) z.z = bit;
            else z.w = bit;
        }
        p[i] = z;
    }
}

__global__ void zero_f(float* p, int n) {
    int i = blockIdx.x * blockDim.x + threadIdx.x;
    if (i < n) p[i] = 0.0f;
}

__global__ void edge_kernel(const int* __restrict__ ei, unsigned* bm) {
    int e = blockIdx.x * blockDim.x + threadIdx.x;
    if (e < EE) {
        int s = ei[e];
        int d = ei[EE + e];
        atomicOr(&bm[s * WPR + (d >> 5)], 1u << (d & 31));
    }
}

// one wave per row: popcount + prefix scan -> ELL cols (ushort), deg, dis
__global__ void extract_kernel(const unsigned* __restrict__ bm,
                               unsigned short* __restrict__ ell, int* __restrict__ deg,
                               float* __restrict__ dis) {
    int gtid = blockIdx.x * blockDim.x + threadIdx.x;
    int row  = gtid >> 6;
    int lane = threadIdx.x & 63;
    if (row >= NN) return;
    const uint4* wp = (const uint4*)(bm + (size_t)row * WPR + lane * 8);
    uint4 a = wp[0];
    uint4 b = wp[1];
    unsigned w[8] = {a.x, a.y, a.z, a.w, b.x, b.y, b.z, b.w};
    int pc = 0;
#pragma unroll
    for (int k = 0; k < 8; k++) pc += __popc(w[k]);
    int pre = pc;
#pragma unroll
    for (int off = 1; off < 64; off <<= 1) {
        int o = __shfl_up(pre, off, 64);
        if (lane >= off) pre += o;
    }
    int total = __shfl(pre, 63, 64);
    pre -= pc;  // exclusive
    int base = row * MAXD;
    int pos = pre;
#pragma unroll
    for (int k = 0; k < 8; k++) {
        unsigned bits = w[k];
        int cbase = lane * 256 + k * 32;
        while (bits) {
            int bit = __ffs(bits) - 1;
            if (pos < MAXD) ell[base + pos] = (unsigned short)(cbase + bit);
            pos++;
            bits &= bits - 1;
        }
    }
    if (lane == 0) {
        deg[row] = total < MAXD ? total : MAXD;
        dis[row] = 1.0f / sqrtf((float)total);
    }
}

// y[row, p*128+c] = (fp16)(dis[row] * sum_k dis[col_k] * src[p][col_k][c])
// Half-wave gather: lane<32 handles neighbor k, lane>=32 neighbor k+1;
// each lane loads ushort4 (8B) -> 512 B per wave VMEM instr; unroll 4
// puts 4 such loads in flight per wave. 8 LDS partials, block reduce.
__global__ __launch_bounds__(256) void spmm_f16(const _Float16* __restrict__ src,
                                                const unsigned short* __restrict__ ell,
                                                const int* __restrict__ deg,
                                                const float* __restrict__ dis,
                                                _Float16* __restrict__ y, int P) {
    __shared__ int2  scw[MAXD];
    __shared__ float red[8][128];
    const int row  = blockIdx.x;
    const int p    = blockIdx.y;
    const int t    = threadIdx.x;
    const int wv   = t >> 6;
    const int lane = t & 63;
    const int half = lane >> 5;
    const int l32  = lane & 31;
    const int d    = deg[row];
    if (t < MAXD) {
        if (t < d) {
            int c = ell[row * MAXD + t];
            scw[t] = make_int2(c, __float_as_int(dis[c]));
        } else {
            scw[t] = make_int2(0, 0);   // weight 0, safe col
        }
    }
    __syncthreads();

    const _Float16* plane = src + (size_t)p * NN * 128;
    float a0 = 0.0f, a1 = 0.0f, a2 = 0.0f, a3 = 0.0f;
#pragma unroll 4
    for (int k = wv * 2 + half; k < d; k += 8) {
        int2 pr = scw[k];
        float wgt = __int_as_float(pr.y);
        ushort4 u = *(const ushort4*)(plane + (size_t)pr.x * 128 + l32 * 4);
        _Float16 f0 = *(_Float16*)&u.x, f1 = *(_Float16*)&u.y;
        _Float16 f2 = *(_Float16*)&u.z, f3 = *(_Float16*)&u.w;
        a0 = fmaf(wgt, (float)f0, a0);
        a1 = fmaf(wgt, (float)f1, a1);
        a2 = fmaf(wgt, (float)f2, a2);
        a3 = fmaf(wgt, (float)f3, a3);
    }
    *(float4*)&red[wv * 2 + half][l32 * 4] = make_float4(a0, a1, a2, a3);
    __syncthreads();
    if (t < 128) {
        float s = 0.0f;
#pragma unroll
        for (int q = 0; q < 8; q++) s += red[q][t];
        y[(size_t)row * (P * 128) + p * 128 + t] = (_Float16)(dis[row] * s);
    }
}

// ================= MFMA GEMM: 128x64 tile, 256 thr / 4 waves ================
// A:[M,K] fp16 row-major. Bt:[256][K] fp16 (pre-transposed W). K-chunk 32.
// Wave (wm,wn): 4 m-tiles x 2 n-tiles of 16x16x32 MFMA.
#define ASTR 40   // f16 stride (80 B, 16B-aligned)
#define BSTR 40

#define MFMA_PROLOG                                                            \
    const int r0 = blockIdx.x * 128;                                           \
    const int c0 = blockIdx.y * 64;                                            \
    const int t = threadIdx.x;                                                 \
    const int lane = t & 63, wv = t >> 6;                                      \
    const int wm = wv >> 1, wn = wv & 1;                                       \
    const int qm = lane & 15, qk = lane >> 4;                                  \
    f4 acc[4][2];                                                              \
    _Pragma("unroll") for (int i = 0; i < 4; i++)                              \
        _Pragma("unroll") for (int j = 0; j < 2; j++)                          \
            acc[i][j] = (f4){0.f, 0.f, 0.f, 0.f};

#define MFMA_KLOOP(Aptr, Wtptr, K)                                             \
    for (int k0 = 0; k0 < K; k0 += 32) {                                       \
        __syncthreads();                                                       \
        {                                                                      \
            int r = t >> 1, ko = (t & 1) * 16;                                 \
            const su8* srcA = (const su8*)(Aptr + (size_t)(r0 + r) * K + k0 + ko); \
            su8 a0 = srcA[0], a1 = srcA[1];                                    \
            *(su8*)&As[r * ASTR + ko]     = a0;                                \
            *(su8*)&As[r * ASTR + ko + 8] = a1;                                \
            int n = t >> 2, ko2 = (t & 3) * 8;                                 \
            *(su8*)&Bs[n * BSTR + ko2] =                                       \
                *(const su8*)(Wtptr + (size_t)(c0 + n) * K + k0 + ko2);        \
        }                                                                      \
        __syncthreads();                                                       \
        h8 bfr[2];                                                             \
        _Pragma("unroll") for (int j = 0; j < 2; j++)                          \
            bfr[j] = *(const h8*)&Bs[(wn * 32 + j * 16 + qm) * BSTR + qk * 8]; \
        _Pragma("unroll") for (int i = 0; i < 4; i++) {                        \
            h8 afr = *(const h8*)&As[(wm * 64 + i * 16 + qm) * ASTR + qk * 8]; \
            _Pragma("unroll") for (int j = 0; j < 2; j++)                      \
                acc[i][j] = __builtin_amdgcn_mfma_f32_16x16x32_f16(            \
                    afr, bfr[j], acc[i][j], 0, 0, 0);                          \
        }                                                                      \
    }

// GEMM1: h1 = relu(y1 @ W1 + b1) -> fp16, 2 column planes [2][NN][128]
template <int K>
__global__ __launch_bounds__(256) void gemm_mfma_f16(
        const _Float16* __restrict__ A, const _Float16* __restrict__ Wt,
        const float* __restrict__ bias, _Float16* __restrict__ H) {
    __shared__ __align__(16) _Float16 As[128 * ASTR];
    __shared__ __align__(16) _Float16 Bs[64 * BSTR];
    __shared__ __align__(16) _Float16 Cs[128 * 72];
    MFMA_PROLOG
    MFMA_KLOOP(A, Wt, K)

    float bv[2];
#pragma unroll
    for (int j = 0; j < 2; j++) bv[j] = bias[c0 + wn * 32 + j * 16 + qm];
#pragma unroll
    for (int i = 0; i < 4; i++)
#pragma unroll
        for (int j = 0; j < 2; j++) {
            int lc = wn * 32 + j * 16 + qm;
#pragma unroll
            for (int rr = 0; rr < 4; rr++) {
                int lr = wm * 64 + i * 16 + qk * 4 + rr;
                Cs[lr * 72 + lc] = (_Float16)fmaxf(acc[i][j][rr] + bv[j], 0.0f);
            }
        }
    __syncthreads();
    {
        int r = t >> 1, half_ = t & 1;
        const int pl = c0 >> 7;
        const int cw = (c0 & 127) + half_ * 32;
        _Float16* dst = H + (size_t)pl * NN * 128 + (size_t)(r0 + r) * 128 + cw;
        const _Float16* srcc = &Cs[r * 72 + half_ * 32];
#pragma unroll
        for (int q = 0; q < 4; q++)
            *(su8*)(dst + q * 8) = *(const su8*)(srcc + q * 8);
    }
}

// GEMM2 + fused mean-pool numerator (no C materialization).
#define NG 8
template <int K>
__global__ __launch_bounds__(256) void gemm_mfma_pool(
        const _Float16* __restrict__ A, const _Float16* __restrict__ Wt,
        const float* __restrict__ bias, const int* __restrict__ batch,
        float* __restrict__ pooled) {
    __shared__ __align__(16) _Float16 As[128 * ASTR];
    __shared__ __align__(16) _Float16 Bs[64 * BSTR];
    __shared__ float pools[NG][68];
    __shared__ int sb[128];
    MFMA_PROLOG
    if (t < 128) sb[t] = batch[r0 + t];
    for (int i = t; i < NG * 68; i += 256) ((float*)pools)[i] = 0.0f;
    MFMA_KLOOP(A, Wt, K)

    float bv[2];
#pragma unroll
    for (int j = 0; j < 2; j++) bv[j] = bias[c0 + wn * 32 + j * 16 + qm];
    __syncthreads();
    const int g0 = sb[0];
#pragma unroll
    for (int i = 0; i < 4; i++)
#pragma unroll
        for (int j = 0; j < 2; j++) {
            int lc = wn * 32 + j * 16 + qm;
#pragma unroll
            for (int rr = 0; rr < 4; rr++) {
                int lr = wm * 64 + i * 16 + qk * 4 + rr;
                int gi = min(sb[lr] - g0, NG - 1);
                float v = fmaxf(acc[i][j][rr] + bv[j], 0.0f);
                atomicAdd(&pools[gi][lc], v);
            }
        }
    __syncthreads();
    const int ng = min(sb[127] - g0 + 1, NG);
    for (int i2 = t; i2 < ng * 64; i2 += 256) {
        int gi = i2 >> 6, c = i2 & 63;
        float v = pools[gi][c];
        if (v != 0.0f) atomicAdd(&pooled[(g0 + gi) * 256 + c0 + c], v);
    }
}

// counts per graph
__global__ void count_kernel(const int* __restrict__ batch, float* cnt) {
    __shared__ int h[GG];
    int t = threadIdx.x;
    if (t < GG) h[t] = 0;
    __syncthreads();
    int i = blockIdx.x * blockDim.x + t;
    if (i < NN) atomicAdd(&h[batch[i]], 1);
    __syncthreads();
    if (t < GG && h[t] > 0) atomicAdd(&cnt[t], (float)h[t]);
}

// out[g,c] = (pooled[g,:]/cnt[g]) . Wc[:,c] + bc[c]
__global__ void head_kernel(const float* __restrict__ pooled,
                            const float* __restrict__ cnt,
                            const float* __restrict__ Wc,
                            const float* __restrict__ bc,
                            float* __restrict__ out) {
    int g = blockIdx.x;
    int l = threadIdx.x;  // 64
    float inv = 1.0f / fmaxf(cnt[g], 1.0f);
    float acc[CDIM];
#pragma unroll
    for (int c = 0; c < CDIM; c++) acc[c] = 0.0f;
    for (int t = l; t < 256; t += 64) {
        float pv = pooled[g * 256 + t] * inv;
#pragma unroll
        for (int c = 0; c < CDIM; c++) acc[c] = fmaf(pv, Wc[t * CDIM + c], acc[c]);
    }
#pragma unroll
    for (int c = 0; c < CDIM; c++) {
        float v = acc[c];
        for (int off = 32; off > 0; off >>= 1) v += __shfl_down(v, off, 64);
        if (l == 0) out[g * CDIM + c] = v + bc[c];
    }
}

extern "C" void kernel_launch(void* const* d_in, const int* in_sizes, int n_in,
                              void* d_out, int out_size, void* d_ws, size_t ws_size,
                              hipStream_t stream) {
    const float* x  = (const float*)d_in[0];
    const int*   ei = (const int*)d_in[1];
    const int*   batch = (const int*)d_in[2];
    const float* W1 = (const float*)d_in[3];
    const float* b1 = (const float*)d_in[4];
    const float* W2 = (const float*)d_in[5];
    const float* b2 = (const float*)d_in[6];
    const float* Wc = (const float*)d_in[7];
    const float* bc = (const float*)d_in[8];
    float* out = (float*)d_out;

    char* ws = (char*)d_ws;
    unsigned* bm   = (unsigned*)(ws + OFF_BM);
    _Float16* y1h  = (_Float16*)(ws + OFF_Y1H);
    _Float16* h1   = (_Float16*)(ws + OFF_H1);
    _Float16* y2h  = (_Float16*)(ws + OFF_Y2H);
    _Float16* xh   = (_Float16*)(ws + OFF_XH);
    unsigned short* ell = (unsigned short*)(ws + OFF_ELL);
    float* dis     = (float*)(ws + OFF_DIS);
    int*   deg     = (int*)(ws + OFF_DEG);
    float* pooled  = (float*)(ws + OFF_POOL);
    float* cnt     = (float*)(ws + OFF_CNT);
    _Float16* wt1  = (_Float16*)(ws + OFF_WT1);
    _Float16* wt2  = (_Float16*)(ws + OFF_WT2);

    // 0) conversions: x -> fp16; W1,W2 -> fp16 transposed
    cvt_f16<<<(NN * DDIM) / 1024, 256, 0, stream>>>(x, xh);
    cvt_wt<<<(256 * DDIM) / 256, 256, 0, stream>>>(W1, wt1, DDIM);
    cvt_wt<<<(256 * HDIM) / 256, 256, 0, stream>>>(W2, wt2, HDIM);
    // 1) zero 32MB bitmap + self-loop bits (fused)
    zero_selfloop<<<2048, 256, 0, stream>>>((uint4*)bm);
    // 2) edges
    edge_kernel<<<EE / 256, 256, 0, stream>>>(ei, bm);
    // 3) bitmap -> ELL(ushort) + deg + dis (wave per row)
    extract_kernel<<<(NN * 64) / 256, 256, 0, stream>>>(bm, ell, deg, dis);
    // 3b) zero pooled+cnt, counts
    zero_f<<<(GG * 256 + GG + 255) / 256, 256, 0, stream>>>(pooled, GG * 256 + GG);
    count_kernel<<<NN / 256, 256, 0, stream>>>(batch, cnt);
    // 4) SpMM1: y1h = Ahat @ xh   [N,128] fp16 (4 MB src, L2-resident)
    {
        dim3 grid(NN, 1);
        spmm_f16<<<grid, 256, 0, stream>>>(xh, ell, deg, dis, y1h, 1);
    }
    // 5) GEMM1 (MFMA): h1 = relu(y1h @ W1 + b1) -> fp16, 2 column planes
    {
        dim3 grid(NN / 128, 256 / 64);
        gemm_mfma_f16<DDIM><<<grid, 256, 0, stream>>>(y1h, wt1, b1, h1);
    }
    // 6) SpMM2: y2h = Ahat @ h1  [N,256] fp16, 2 passes (4 MB plane each)
    {
        dim3 grid(NN, 2);
        spmm_f16<<<grid, 256, 0, stream>>>(h1, ell, deg, dis, y2h, 2);
    }
    // 7) GEMM2 (MFMA) + fused pooling numerator
    {
        dim3 grid(NN / 128, 256 / 64);
        gemm_mfma_pool<HDIM><<<grid, 256, 0, stream>>>(y2h, wt2, b2, batch, pooled);
    }
    // 8) head
    head_kernel<<<GG, 64, 0, stream>>>(pooled, cnt, Wc, bc, out);
}